// Round 16
// baseline (679.451 us; speedup 1.0000x reference)
//
#include <hip/hip_runtime.h>
#include <hip/hip_bf16.h>
#include <math.h>

#define T_TOK 2048
#define B_SZ 2
#define L_SEQ 1024
#define D_MOD 1024
#define N_H 16
#define N_KV 4
#define N_CH 8
#define N_E 8
#define FF_DIM 4096
#define DC_K 4
#define EPS_F 1e-6f

typedef unsigned short u16;
typedef unsigned int u32;
typedef short s16x8 __attribute__((ext_vector_type(8)));
typedef u16 u16x8 __attribute__((ext_vector_type(8)));
typedef float f32x4 __attribute__((ext_vector_type(4)));
struct alignas(8) U16x4 { u16 a, b, c, d; };

// lgkm-only barrier: orders LDS traffic without draining in-flight VMEM prefetch
#define BAR_LGKM() asm volatile("s_waitcnt lgkmcnt(0)\n\ts_barrier" ::: "memory")

__device__ __forceinline__ float gelu_exact(float x) {
    return 0.5f * x * (1.0f + erff(x * 0.70710678118654752f));
}
__device__ __forceinline__ u16 f2bf(float f) {  // RNE
    u32 x = __float_as_uint(f);
    return (u16)((x + 0x7fffu + ((x >> 16) & 1u)) >> 16);
}
__device__ __forceinline__ float b2f(u16 u) {
    return __uint_as_float(((u32)u) << 16);
}
__device__ __forceinline__ void gload_lds16(const u16* g, u16* l) {
    __builtin_amdgcn_global_load_lds(
        (const __attribute__((address_space(1))) u32*)g,
        (__attribute__((address_space(3))) u32*)l, 16, 0, 0);
}
// XOR chunk swizzle: cpr=4 (BK=32) -> 2-bit, cpr=8 (BK=64) -> 3-bit
__device__ __forceinline__ int swz(int row, int ch, int cpr) {
    return (cpr == 4) ? (ch ^ ((row >> 1) & 3)) : (ch ^ (row & 7));
}

// ---------------- small-weight transpose + fp32->bf16 (one tile per block) ----------------
struct TDesc {
    const float* src;
    u16* dst;
    int R, C, dstStride, dstRowOff, tileBase, nPerMat;
};
struct TPack { TDesc d[10]; };

__global__ __launch_bounds__(256) void transpose_all(TPack p) {
    __shared__ float ts[64][65];
    int t = blockIdx.x;
    int i = 0;
#pragma unroll
    for (int j = 1; j < 10; ++j)
        if (t >= p.d[j].tileBase) i = j;
    TDesc d = p.d[i];
    int local = t - d.tileBase;
    int e = local / d.nPerMat;
    local -= e * d.nPerMat;
    int ntx = d.C >> 6;
    int bx = local % ntx, by = local / ntx;
    const float* src = d.src + (size_t)e * d.R * d.C + (size_t)(by * 64) * d.C + bx * 64;
    u16* dst = d.dst + (size_t)e * d.C * d.dstStride +
               (size_t)(d.dstRowOff + bx * 64) * d.dstStride + by * 64;
    int tid = threadIdx.x;
#pragma unroll
    for (int k = 0; k < 4; ++k) {
        int fidx = k * 256 + tid;
        int r = fidx >> 4, c4 = (fidx & 15) << 2;
        float4 v = *(const float4*)(src + (size_t)r * d.C + c4);
        ts[r][c4] = v.x; ts[r][c4 + 1] = v.y; ts[r][c4 + 2] = v.z; ts[r][c4 + 3] = v.w;
    }
    __syncthreads();
#pragma unroll
    for (int k = 0; k < 2; ++k) {
        int idx = k * 256 + tid;
        int c = idx >> 3, r8 = (idx & 7) << 3;
        u16x8 o;
#pragma unroll
        for (int j = 0; j < 8; ++j) o[j] = f2bf(ts[r8 + j][c]);
        *(u16x8*)(dst + (size_t)c * d.dstStride + r8) = o;
    }
}

// ---------------- RMSNorm: fp32 in, optional fp32 + bf16 out ----------------
__global__ __launch_bounds__(256) void rmsnorm_kernel(const float* __restrict__ x,
                                                      const float* __restrict__ w,
                                                      float* __restrict__ fo,
                                                      u16* __restrict__ bo) {
    int row = blockIdx.x;
    int tid = threadIdx.x;
    const float* xr = x + (size_t)row * D_MOD;
    float4 v = ((const float4*)xr)[tid];
    float ss = v.x * v.x + v.y * v.y + v.z * v.z + v.w * v.w;
    __shared__ float red[256];
    red[tid] = ss;
    __syncthreads();
    for (int s = 128; s > 0; s >>= 1) {
        if (tid < s) red[tid] += red[tid + s];
        __syncthreads();
    }
    float inv = 1.0f / sqrtf(red[0] * (1.0f / D_MOD) + EPS_F);
    float4 wv = ((const float4*)w)[tid];
    float4 o;
    o.x = v.x * inv * wv.x;
    o.y = v.y * inv * wv.y;
    o.z = v.z * inv * wv.z;
    o.w = v.w * inv * wv.w;
    if (fo) ((float4*)(fo + (size_t)row * D_MOD))[tid] = o;
    if (bo) {
        U16x4 b;
        b.a = f2bf(o.x); b.b = f2bf(o.y); b.c = f2bf(o.z); b.d = f2bf(o.w);
        *(U16x4*)(bo + (size_t)row * D_MOD + tid * 4) = b;
    }
}

// ---------------- MFMA bf16 GEMM (BM x BN, BK in {32,64}) + optional transpose tail ----------------
// MODE 0 dense / 1 MoE gather / 2 MoE compact / 3 MoE compact split-K=2 (f32 partials).
template <int MODE, int GELU, int OUTF, int OUTB, int BM, int BN, int BK, int TW>
__global__ __launch_bounds__(256) void mfma_gemm(const u16* __restrict__ A,
                                                 const u16* __restrict__ BT,
                                                 const float* __restrict__ bias,
                                                 const float* __restrict__ res,
                                                 float* __restrict__ C,
                                                 u16* __restrict__ Cb,
                                                 const int* __restrict__ list,
                                                 const int* __restrict__ offs,
                                                 const int* __restrict__ counts,
                                                 int M, int N, int K, int nx,
                                                 const float* __restrict__ tW1,
                                                 const float* __restrict__ tW2,
                                                 u16* __restrict__ tW1T,
                                                 u16* __restrict__ tW2T,
                                                 int tLo, int tHi) {
    constexpr int PWR = BM / 2;
    constexpr int PWC = BN / 2;
    constexpr int MI = PWR / 16;
    constexpr int NI = PWC / 16;
    constexpr int CPR = BK / 8;
    constexpr int AISS = (BM * CPR) / 64;
    constexpr int BISS = (BN * CPR) / 64;
    constexpr int APW = (AISS >= 4) ? (AISS / 4) : 1;
    constexpr int BPW = BISS / 4;
    constexpr int SMG = (2 * BM * BK + 2 * BN * BK) * 2;
    constexpr int SMT = TW ? (64 * 65 * 4) : 0;
    constexpr int SM = SMG > SMT ? SMG : SMT;
    __shared__ alignas(16) char smem[SM];
    u16* ldsA = (u16*)smem;
    u16* ldsB = ldsA + 2 * BM * BK;
    int tid = threadIdx.x;
    int lane = tid & 63, w = tid >> 6;
    int wr = w >> 1, wc = w & 1;
    int bx, by, e, sk = 0;
    if (MODE == 0) {
        bx = blockIdx.x; by = blockIdx.y; e = 0;
    } else if (MODE == 3) {
        int id = blockIdx.x;
        e = id & 7;
        int r = id >> 3;
        sk = r & 1;
        int q = r >> 1;
        bx = q % nx;
        by = q / nx;
    } else {
        int id = blockIdx.x;
        e = id & 7;
        int r = id >> 3;
        bx = r % nx;
        by = r / nx;
    }
    int cnt, off;
    if (MODE == 0) { cnt = M; off = 0; }
    else { cnt = counts[e]; off = offs[e]; }
    int m0 = by * BM;
    if (m0 < cnt) {  // GEMM body
        int n0 = bx * BN;
        const u16* Bt = BT + (size_t)e * (size_t)N * K;
        int kLo = 0, kHi = K;
        if (MODE == 3) { kLo = sk * (K >> 1); kHi = kLo + (K >> 1); }

        const u16* aSrc[APW];
        const u16* bSrc[BPW];
#pragma unroll
        for (int jp = 0; jp < APW; ++jp) {
            int ii = (AISS >= 4) ? (jp * 4 + w) : w;
            int ci = ii * 64 + lane;
            int rowA = ci / CPR, ch = ci % CPR;
            int rl = m0 + ((rowA < BM) ? rowA : (BM - 1));
            if (rl >= cnt) rl = cnt - 1;
            size_t ga;
            if (MODE == 1) ga = (size_t)list[off + rl] * K;
            else if (MODE >= 2) ga = (size_t)(off + rl) * K;
            else ga = (size_t)rl * K;
            aSrc[jp] = A + ga + (swz(rowA, ch, CPR) << 3);
        }
#pragma unroll
        for (int jp = 0; jp < BPW; ++jp) {
            int ii = jp * 4 + w;
            int ci = ii * 64 + lane;
            int rowB = ci / CPR, ch = ci % CPR;
            bSrc[jp] = Bt + (size_t)(n0 + rowB) * K + (swz(rowB, ch, CPR) << 3);
        }

        auto stage = [&](int buf, int k0) {
#pragma unroll
            for (int jp = 0; jp < APW; ++jp) {
                if (AISS >= 4 || w < AISS) {
                    int ii = (AISS >= 4) ? (jp * 4 + w) : w;
                    gload_lds16(aSrc[jp] + k0, ldsA + buf * (BM * BK) + ii * 512);
                }
            }
#pragma unroll
            for (int jp = 0; jp < BPW; ++jp) {
                int ii = jp * 4 + w;
                gload_lds16(bSrc[jp] + k0, ldsB + buf * (BN * BK) + ii * 512);
            }
        };

        f32x4 acc[MI][NI] = {};
        int r16 = lane & 15, cr = lane >> 4;

        stage(0, kLo);
        __syncthreads();
        int cur = 0;
        for (int k0 = kLo; k0 < kHi; k0 += BK) {
            if (k0 + BK < kHi) stage(cur ^ 1, k0 + BK);
#pragma unroll
            for (int hh = 0; hh < BK / 32; ++hh) {
                s16x8 af[MI], bfr[NI];
#pragma unroll
                for (int mi = 0; mi < MI; ++mi) {
                    int row = wr * PWR + mi * 16 + r16;
                    af[mi] = *(const s16x8*)&ldsA[cur * (BM * BK) + row * BK +
                                                  (swz(row, hh * 4 + cr, CPR) << 3)];
                }
#pragma unroll
                for (int ni = 0; ni < NI; ++ni) {
                    int row = wc * PWC + ni * 16 + r16;
                    bfr[ni] = *(const s16x8*)&ldsB[cur * (BN * BK) + row * BK +
                                                   (swz(row, hh * 4 + cr, CPR) << 3)];
                }
#pragma unroll
                for (int mi = 0; mi < MI; ++mi)
#pragma unroll
                    for (int ni = 0; ni < NI; ++ni)
                        acc[mi][ni] = __builtin_amdgcn_mfma_f32_16x16x32_bf16(
                            af[mi], bfr[ni], acc[mi][ni], 0, 0, 0);
            }
            __syncthreads();
            cur ^= 1;
        }

        const float* bias_e = bias ? (bias + ((MODE && MODE != 3) ? (size_t)e * N : 0)) : nullptr;
        float* Cp = C ? (C + (MODE == 3 ? (size_t)sk * ((size_t)2 * T_TOK * 1024) : (size_t)0))
                      : nullptr;
#pragma unroll
        for (int mi = 0; mi < MI; ++mi) {
#pragma unroll
            for (int ni = 0; ni < NI; ++ni) {
                int rloc = wr * PWR + mi * 16 + (lane >> 4) * 4;
                int col = n0 + wc * PWC + ni * 16 + (lane & 15);
#pragma unroll
                for (int jj = 0; jj < 4; ++jj) {
                    int rl = m0 + rloc + jj;
                    if (rl >= cnt) continue;
                    float val = acc[mi][ni][jj];
                    if (bias_e) val += bias_e[col];
                    if (GELU) val = gelu_exact(val);
                    size_t crow = (MODE == 0) ? (size_t)rl : (size_t)(off + rl);
                    if (res) val += res[crow * N + col];
                    if (OUTF) Cp[crow * N + col] = val;
                    if (OUTB) Cb[crow * N + col] = f2bf(val);
                }
            }
        }
    }

    if constexpr (TW) {
        int nb = gridDim.x * gridDim.y;
        int bid = blockIdx.y * gridDim.x + blockIdx.x;
        float (*ts)[65] = (float(*)[65])smem;
        __syncthreads();
        for (int t = tLo + bid; t < tHi; t += nb) {
            const float* src;
            u16* dst;
            int Cc, ds;
            if (t < 8192) {
                int ee = t >> 10, loc = t & 1023;
                int tbx = loc & 63, tby = loc >> 6;
                src = tW1 + (size_t)ee * 1024 * FF_DIM + (size_t)(tby << 6) * FF_DIM + (tbx << 6);
                dst = tW1T + (size_t)ee * FF_DIM * 1024 + (size_t)(tbx << 6) * 1024 + (tby << 6);
                Cc = FF_DIM; ds = 1024;
            } else {
                int tt = t - 8192;
                int ee = tt >> 10, loc = tt & 1023;
                int tbx = loc & 15, tby = loc >> 4;
                src = tW2 + (size_t)ee * FF_DIM * 1024 + (size_t)(tby << 6) * 1024 + (tbx << 6);
                dst = tW2T + (size_t)ee * 1024 * FF_DIM + (size_t)(tbx << 6) * FF_DIM + (tby << 6);
                Cc = 1024; ds = FF_DIM;
            }
#pragma unroll
            for (int k = 0; k < 4; ++k) {
                int fidx = k * 256 + tid;
                int r = fidx >> 4, c4 = (fidx & 15) << 2;
                float4 v = *(const float4*)(src + (size_t)r * Cc + c4);
                ts[r][c4] = v.x; ts[r][c4 + 1] = v.y; ts[r][c4 + 2] = v.z; ts[r][c4 + 3] = v.w;
            }
            __syncthreads();
#pragma unroll
            for (int k = 0; k < 2; ++k) {
                int idx = k * 256 + tid;
                int c = idx >> 3, r8 = (idx & 7) << 3;
                u16x8 o;
#pragma unroll
                for (int j = 0; j < 8; ++j) o[j] = f2bf(ts[r8 + j][c]);
                *(u16x8*)(dst + (size_t)c * ds + r8) = o;
            }
            __syncthreads();
        }
    }
}

// ---------------- MFMA flash attention, double-buffered K/V with prefetch ----------------
// Per tile: write Vt[cur] -> full barrier (drains old prefetch) -> issue K gload +
// V reg-loads for tile kt+1 (in flight across entire compute) -> QK/softmax/P (lgkm-only
// barrier) /PV. Only the prologue exposes a full staging latency.
template <int HD>
__global__ __launch_bounds__(256) void mfma_attn(const u16* __restrict__ Qb,
                                                 const u16* __restrict__ Kb,
                                                 const u16* __restrict__ Vb,
                                                 u16* __restrict__ O,
                                                 int stride, int ostride,
                                                 int nh, int nkv, float scale) {
    constexpr int KT = 64;
    constexpr int CH = HD / 8;
    constexpr int NF = HD / 32;
    constexpr int ND = HD / 16;
    constexpr int VSTR = 72;
    constexpr int NISS = (64 * CH) / (64 * 4);
    constexpr int NH2 = HD / 64;

    __shared__ u16 Kl[2][64 * HD];
    __shared__ u16 Vt[2][HD * VSTR];
    __shared__ u16 Pl[4][16 * 72];

    int tid = threadIdx.x, lane = tid & 63, w = tid >> 6;
    int g = lane >> 4, r16 = lane & 15;
    int q0 = blockIdx.x * 64, h = blockIdx.y, b = blockIdx.z;
    int kvh = h / (nh / nkv);

    const u16* Qp = Qb + (size_t)(b * L_SEQ + q0 + w * 16 + r16) * stride + h * HD + g * 8;
    s16x8 qf[NF];
#pragma unroll
    for (int f = 0; f < NF; ++f) qf[f] = *(const s16x8*)(Qp + f * 32);

    const u16* Kbase = Kb + (size_t)(b * L_SEQ) * stride + (size_t)kvh * HD;
    const u16* Vbase = Vb + (size_t)(b * L_SEQ) * stride + (size_t)kvh * HD;

    int srcOffK[NISS];
#pragma unroll
    for (int i = 0; i < NISS; ++i) {
        int ci = (w * NISS + i) * 64 + lane;
        int row = ci / CH;
        int ch = ci % CH;
        srcOffK[i] = row * stride + ((ch ^ (row & 7)) << 3);
    }

    u16x8 vr[2 * NH2];
    auto vload = [&](int kt) {
        const u16* Vs = Vbase + (size_t)(kt * KT) * stride + (size_t)lane * stride;
#pragma unroll
        for (int half = 0; half < NH2; ++half) {
            int dbase = w * 16 + half * 64;
            vr[2 * half] = *(const u16x8*)(Vs + dbase);
            vr[2 * half + 1] = *(const u16x8*)(Vs + dbase + 8);
        }
    };

    f32x4 ofr[ND] = {};
    float m_r[4], l_r[4];
#pragma unroll
    for (int r = 0; r < 4; ++r) { m_r[r] = -1e30f; l_r[r] = 0.f; }

    constexpr int NT = L_SEQ / KT;
    // prologue: stage tile 0
#pragma unroll
    for (int i = 0; i < NISS; ++i)
        gload_lds16(Kbase + srcOffK[i], &Kl[0][(w * NISS + i) * 512]);
    vload(0);

    for (int kt = 0; kt < NT; ++kt) {
        int cur = kt & 1;
        // write V regs (tile kt) into Vt[cur]
#pragma unroll
        for (int half = 0; half < NH2; ++half) {
            int dbase = w * 16 + half * 64;
#pragma unroll
            for (int j = 0; j < 8; ++j) {
                Vt[cur][(dbase + j) * VSTR + lane] = vr[2 * half][j];
                Vt[cur][(dbase + 8 + j) * VSTR + lane] = vr[2 * half + 1][j];
            }
        }
        __syncthreads();  // drains K gload (tile kt) + orders Vt writes
        if (kt + 1 < NT) {  // prefetch tile kt+1; stays in flight through compute
            const u16* Ksrc2 = Kbase + (size_t)((kt + 1) * KT) * stride;
#pragma unroll
            for (int i = 0; i < NISS; ++i)
                gload_lds16(Ksrc2 + srcOffK[i], &Kl[cur ^ 1][(w * NISS + i) * 512]);
            vload(kt + 1);
        }

        f32x4 s[4];
        __builtin_amdgcn_s_setprio(1);
#pragma unroll
        for (int sub = 0; sub < 4; ++sub) {
            f32x4 acc = {};
#pragma unroll
            for (int f = 0; f < NF; ++f) {
                int row = sub * 16 + r16;
                int chunk = (f * 4 + g) ^ (row & 7);
                s16x8 kf = *(const s16x8*)&Kl[cur][(row * CH + chunk) * 8];
                acc = __builtin_amdgcn_mfma_f32_16x16x32_bf16(qf[f], kf, acc, 0, 0, 0);
            }
            s[sub] = acc;
        }
        __builtin_amdgcn_s_setprio(0);

#pragma unroll
        for (int sub = 0; sub < 4; ++sub)
#pragma unroll
            for (int r = 0; r < 4; ++r) s[sub][r] *= scale;
#pragma unroll
        for (int r = 0; r < 4; ++r) {
            float mx = fmaxf(fmaxf(s[0][r], s[1][r]), fmaxf(s[2][r], s[3][r]));
            mx = fmaxf(mx, __shfl_xor(mx, 1));
            mx = fmaxf(mx, __shfl_xor(mx, 2));
            mx = fmaxf(mx, __shfl_xor(mx, 4));
            mx = fmaxf(mx, __shfl_xor(mx, 8));
            float mo = m_r[r];
            float mn = fmaxf(mo, mx);
            float sc = __expf(mo - mn);
            m_r[r] = mn;
            float sum = 0.f;
#pragma unroll
            for (int sub = 0; sub < 4; ++sub) {
                float e = __expf(s[sub][r] - mn);
                s[sub][r] = e;
                sum += e;
            }
            sum += __shfl_xor(sum, 1);
            sum += __shfl_xor(sum, 2);
            sum += __shfl_xor(sum, 4);
            sum += __shfl_xor(sum, 8);
            l_r[r] = l_r[r] * sc + sum;
#pragma unroll
            for (int dsub = 0; dsub < ND; ++dsub) ofr[dsub][r] *= sc;
        }

        u16* Pw = Pl[w];
#pragma unroll
        for (int sub = 0; sub < 4; ++sub)
#pragma unroll
            for (int r = 0; r < 4; ++r) {
                int q = g * 4 + r;
                int k = sub * 16 + r16;
                Pw[q * 72 + (((k >> 3) ^ (q & 7)) << 3) + (k & 7)] = f2bf(s[sub][r]);
            }
        BAR_LGKM();  // P ordering only; VMEM prefetch stays in flight

        s16x8 pf[2];
#pragma unroll
        for (int ks = 0; ks < 2; ++ks) {
            int chunk = (ks * 4 + g) ^ (r16 & 7);
            pf[ks] = *(const s16x8*)&Pw[r16 * 72 + chunk * 8];
        }
        __builtin_amdgcn_s_setprio(1);
#pragma unroll
        for (int dsub = 0; dsub < ND; ++dsub)
#pragma unroll
            for (int ks = 0; ks < 2; ++ks) {
                s16x8 vf = *(const s16x8*)&Vt[cur][(dsub * 16 + r16) * VSTR + ks * 32 + g * 8];
                ofr[dsub] = __builtin_amdgcn_mfma_f32_16x16x32_bf16(pf[ks], vf, ofr[dsub], 0, 0, 0);
            }
        __builtin_amdgcn_s_setprio(0);
    }

    float inv[4];
#pragma unroll
    for (int r = 0; r < 4; ++r) inv[r] = 1.0f / l_r[r];
#pragma unroll
    for (int dsub = 0; dsub < ND; ++dsub)
#pragma unroll
        for (int r = 0; r < 4; ++r) {
            int q = q0 + w * 16 + g * 4 + r;
            O[(size_t)(b * L_SEQ + q) * ostride + h * HD + dsub * 16 + r16] =
                f2bf(ofr[dsub][r] * inv[r]);
        }
}

// ---------------- DeltaNet conv + gate (vectorized u16x8) ----------------
__global__ __launch_bounds__(256) void conv_gate_kernel(const u16* __restrict__ gv,
                                                        const float* __restrict__ cw,
                                                        const float* __restrict__ cb,
                                                        u16* __restrict__ gated) {
    int idx = blockIdx.x * 256 + threadIdx.x;
    if (idx >= T_TOK * D_MOD / 8) return;
    int d8 = (idx & 127) << 3;
    int t = idx >> 7;
    int l = t & (L_SEQ - 1);
    float conv[8];
#pragma unroll
    for (int j = 0; j < 8; ++j) conv[j] = cb[d8 + j];
#pragma unroll
    for (int i = 0; i < DC_K; ++i) {
        int lp = l - (DC_K - 1) + i;
        if (lp >= 0) {
            u16x8 v8 = *(const u16x8*)(gv + (size_t)(t - l + lp) * (2 * D_MOD) + D_MOD + d8);
#pragma unroll
            for (int j = 0; j < 8; ++j) conv[j] += b2f(v8[j]) * cw[(d8 + j) * DC_K + i];
        }
    }
    u16x8 g8 = *(const u16x8*)(gv + (size_t)t * (2 * D_MOD) + d8);
    u16x8 o;
#pragma unroll
    for (int j = 0; j < 8; ++j) {
        float gate = b2f(g8[j]);
        float sig = 1.0f / (1.0f + expf(-gate));
        o[j] = f2bf(conv[j] * (gate * sig));
    }
    *(u16x8*)(gated + (size_t)t * D_MOD + d8) = o;
}

// ---------------- MoE routing (fp32 input) ----------------
__global__ __launch_bounds__(256) void route_kernel(const float* __restrict__ g,
                                                    const float* __restrict__ wg,
                                                    int* __restrict__ tIdx,
                                                    float* __restrict__ tScore,
                                                    int* __restrict__ counts) {
    int t = blockIdx.x, tid = threadIdx.x;
    __shared__ float gs[D_MOD];
    __shared__ float logits[N_E];
    ((float4*)gs)[tid] = ((const float4*)(g + (size_t)t * D_MOD))[tid];
    __syncthreads();
    int e = tid >> 5, lane = tid & 31;
    const float* w = wg + (size_t)e * D_MOD;
    float p = 0.f;
    for (int d = lane; d < D_MOD; d += 32) p += gs[d] * w[d];
    for (int o = 16; o > 0; o >>= 1) p += __shfl_down(p, o, 32);
    if (lane == 0) logits[e] = p;
    __syncthreads();
    if (tid == 0) {
        float mx = logits[0];
        for (int e2 = 1; e2 < N_E; ++e2) mx = fmaxf(mx, logits[e2]);
        float pe[N_E];
        float Z = 0.f;
        for (int e2 = 0; e2 < N_E; ++e2) {
            pe[e2] = expf(logits[e2] - mx);
            Z += pe[e2];
        }
        int i0 = 0;
        float b0 = pe[0];
        for (int e2 = 1; e2 < N_E; ++e2)
            if (pe[e2] > b0) { b0 = pe[e2]; i0 = e2; }
        int i1 = -1;
        float b1 = -1.f;
        for (int e2 = 0; e2 < N_E; ++e2)
            if (e2 != i0 && pe[e2] > b1) { b1 = pe[e2]; i1 = e2; }
        float invZ = 1.0f / Z;
        tIdx[t * 2] = i0;
        tIdx[t * 2 + 1] = i1;
        tScore[t * 2] = b0 * invZ;
        tScore[t * 2 + 1] = b1 * invZ;
        atomicAdd(&counts[i0], 1);
        atomicAdd(&counts[i1], 1);
    }
}

__global__ void prefix_kernel(const int* __restrict__ counts, int* __restrict__ offs,
                              int* __restrict__ cursor) {
    if (threadIdx.x == 0) {
        int acc = 0;
        for (int e = 0; e < N_E; ++e) {
            offs[e] = acc;
            acc += counts[e];
            cursor[e] = 0;
        }
    }
}

__global__ __launch_bounds__(256) void fill_kernel(const int* __restrict__ tIdx,
                                                   const int* __restrict__ offs,
                                                   int* __restrict__ cursor,
                                                   int* __restrict__ list,
                                                   int* __restrict__ pairRow) {
    int t = blockIdx.x * 256 + threadIdx.x;
    if (t >= T_TOK) return;
    for (int kk = 0; kk < 2; ++kk) {
        int e = tIdx[t * 2 + kk];
        int pos = atomicAdd(&cursor[e], 1);
        int slot = offs[e] + pos;
        list[slot] = t;
        pairRow[t * 2 + kk] = slot;
    }
}

// ---------------- fused MoE combine (split-K partials + bias) + final RMSNorm ----------------
__global__ __launch_bounds__(256) void combine_rms_kernel(const float* __restrict__ yp,
                                                          const float* __restrict__ b2,
                                                          const float* __restrict__ tScore,
                                                          const int* __restrict__ pairRow,
                                                          const int* __restrict__ tIdx,
                                                          const float* __restrict__ h,
                                                          const float* __restrict__ w,
                                                          float* __restrict__ out) {
    const size_t HALF = (size_t)2 * T_TOK * D_MOD;
    int row = blockIdx.x;
    int tid = threadIdx.x;
    float4 v = ((const float4*)(h + (size_t)row * D_MOD))[tid];
#pragma unroll
    for (int kk = 0; kk < 2; ++kk) {
        int r = pairRow[row * 2 + kk];
        int e = tIdx[row * 2 + kk];
        float s = tScore[row * 2 + kk];
        float4 y0 = ((const float4*)(yp + (size_t)r * D_MOD))[tid];
        float4 y1 = ((const float4*)(yp + HALF + (size_t)r * D_MOD))[tid];
        float4 bb = ((const float4*)(b2 + (size_t)e * D_MOD))[tid];
        v.x += s * (y0.x + y1.x + bb.x);
        v.y += s * (y0.y + y1.y + bb.y);
        v.z += s * (y0.z + y1.z + bb.z);
        v.w += s * (y0.w + y1.w + bb.w);
    }
    __shared__ float red[256];
    red[tid] = v.x * v.x + v.y * v.y + v.z * v.z + v.w * v.w;
    __syncthreads();
    for (int s = 128; s > 0; s >>= 1) {
        if (tid < s) red[tid] += red[tid + s];
        __syncthreads();
    }
    float inv = 1.0f / sqrtf(red[0] * (1.0f / D_MOD) + EPS_F);
    float4 wv = ((const float4*)w)[tid];
    float4 o;
    o.x = v.x * inv * wv.x;
    o.y = v.y * inv * wv.y;
    o.z = v.z * inv * wv.z;
    o.w = v.w * inv * wv.w;
    ((float4*)(out + (size_t)row * D_MOD))[tid] = o;
}

extern "C" void kernel_launch(void* const* d_in, const int* in_sizes, int n_in,
                              void* d_out, int out_size, void* d_ws, size_t ws_size,
                              hipStream_t stream) {
    const float* x = (const float*)d_in[0];
    const float* w_rms1 = (const float*)d_in[2];
    const float* w_rms2 = (const float*)d_in[3];
    const float* w_rms3 = (const float*)d_in[4];
    const float* w_rms4 = (const float*)d_in[5];
    const float* Wq = (const float*)d_in[6];
    const float* Wk = (const float*)d_in[7];
    const float* Wv = (const float*)d_in[8];
    const float* Wo = (const float*)d_in[9];
    const float* Cq = (const float*)d_in[10];
    const float* Ck = (const float*)d_in[11];
    const float* Cv = (const float*)d_in[12];
    const float* Co = (const float*)d_in[13];
    const float* Wi = (const float*)d_in[14];
    const float* bi = (const float*)d_in[15];
    const float* conv_w = (const float*)d_in[16];
    const float* conv_b = (const float*)d_in[17];
    const float* Wod = (const float*)d_in[18];
    const float* bod = (const float*)d_in[19];
    const float* w_gate = (const float*)d_in[20];
    const float* W1 = (const float*)d_in[21];
    const float* b1 = (const float*)d_in[22];
    const float* W2 = (const float*)d_in[23];
    const float* b2 = (const float*)d_in[24];
    float* out = (float*)d_out;

    char* ws = (char*)d_ws;
    size_t off = 0;
    auto alloc_f = [&](size_t n) { float* p = (float*)(ws + off); off += n * 4; return p; };
    auto alloc_b = [&](size_t n) { u16* p = (u16*)(ws + off); off += n * 2; return p; };

    u16* qkvT = alloc_b((size_t)1536 * 1024);
    u16* cqkvT = alloc_b((size_t)3072 * 1024);
    u16* WoT = alloc_b((size_t)1024 * 1024);
    u16* CoT = alloc_b((size_t)1024 * 1024);
    u16* WiT = alloc_b((size_t)2048 * 1024);
    u16* WodT = alloc_b((size_t)1024 * 1024);
    u16* W1T = alloc_b((size_t)N_E * FF_DIM * 1024);
    u16* W2T = alloc_b((size_t)N_E * 1024 * FF_DIM);
    const size_t TD = (size_t)T_TOK * D_MOD;
    float* h = alloc_f(TD);
    float* nrm = alloc_f(TD);
    u16* nrm_bf = alloc_b(TD);
    u16* h_bf = alloc_b(TD);
    u16* ab_bf = alloc_b(TD);
    u16* qkv_bf = alloc_b((size_t)T_TOK * 3072);
    u16* gv_bf = alloc_b((size_t)T_TOK * 2048);
    u16* hsel = alloc_b((size_t)2 * T_TOK * FF_DIM);
    float* ypart = alloc_f((size_t)2 * 2 * T_TOK * D_MOD);
    int* counts = (int*)(ws + off); off += N_E * 4;
    int* offs = (int*)(ws + off); off += N_E * 4;
    int* cursor = (int*)(ws + off); off += N_E * 4;
    int* tIdx = (int*)(ws + off); off += 2 * T_TOK * 4;
    int* list = (int*)(ws + off); off += 2 * T_TOK * 4;
    int* pairRow = (int*)(ws + off); off += 2 * T_TOK * 4;
    float* tScore = alloc_f(2 * T_TOK);

    // ---- 0. small-weight transposes ----
    TPack tp;
    int tb = 0;
    auto mkd = [&](int i, const float* s, u16* d, int R, int C, int ds, int ro) {
        int per = (C >> 6) * (R >> 6);
        tp.d[i] = TDesc{s, d, R, C, ds, ro, tb, per};
        tb += per;
    };
    mkd(0, Wq, qkvT, 1024, 1024, 1024, 0);
    mkd(1, Wk, qkvT, 1024, 256, 1024, 1024);
    mkd(2, Wv, qkvT, 1024, 256, 1024, 1280);
    mkd(3, Cq, cqkvT, 1024, 1024, 1024, 0);
    mkd(4, Ck, cqkvT, 1024, 1024, 1024, 1024);
    mkd(5, Cv, cqkvT, 1024, 1024, 1024, 2048);
    mkd(6, Wo, WoT, 1024, 1024, 1024, 0);
    mkd(7, Co, CoT, 1024, 1024, 1024, 0);
    mkd(8, Wi, WiT, 1024, 2048, 1024, 0);
    mkd(9, Wod, WodT, 1024, 1024, 1024, 0);
    transpose_all<<<tb, 256, 0, stream>>>(tp);

    // ---- 1. attn1; dense GEMMs (BK=64) carry W1/W2 transpose tiles ----
    rmsnorm_kernel<<<T_TOK, 256, 0, stream>>>(x, w_rms1, nullptr, nrm_bf);
    mfma_gemm<0, 0, 0, 1, 32, 128, 64, 1><<<dim3(12, 64, 1), 256, 0, stream>>>(
        nrm_bf, qkvT, nullptr, nullptr, nullptr, qkv_bf, nullptr, nullptr, nullptr,
        T_TOK, 1536, 1024, 0, W1, W2, W1T, W2T, 0, 2600);
    mfma_attn<64><<<dim3(16, N_H, B_SZ), 256, 0, stream>>>(
        qkv_bf, qkv_bf + 1024, qkv_bf + 1280, ab_bf, 1536, 1024, N_H, N_KV, 0.125f);
    mfma_gemm<0, 0, 1, 1, 32, 128, 64, 1><<<dim3(8, 64, 1), 256, 0, stream>>>(
        ab_bf, WoT, nullptr, x, h, h_bf, nullptr, nullptr, nullptr,
        T_TOK, 1024, 1024, 0, W1, W2, W1T, W2T, 2600, 4300);

    // ---- 2. ContextManager attention ----
    mfma_gemm<0, 0, 0, 1, 32, 128, 64, 1><<<dim3(24, 64, 1), 256, 0, stream>>>(
        h_bf, cqkvT, nullptr, nullptr, nullptr, qkv_bf, nullptr, nullptr, nullptr,
        T_TOK, 3072, 1024, 0, W1, W2, W1T, W2T, 4300, 9500);
    mfma_attn<128><<<dim3(16, N_CH, B_SZ), 256, 0, stream>>>(
        qkv_bf, qkv_bf + 1024, qkv_bf + 2048, ab_bf, 3072, 1024, N_CH, N_CH,
        0.088388347648318447f);
    mfma_gemm<0, 0, 1, 0, 32, 128, 64, 1><<<dim3(8, 64, 1), 256, 0, stream>>>(
        ab_bf, CoT, nullptr, h, h, nullptr, nullptr, nullptr, nullptr,
        T_TOK, 1024, 1024, 0, W1, W2, W1T, W2T, 9500, 11200);

    // ---- 3. deltanet ----
    rmsnorm_kernel<<<T_TOK, 256, 0, stream>>>(h, w_rms2, nullptr, nrm_bf);
    mfma_gemm<0, 0, 0, 1, 32, 128, 64, 1><<<dim3(16, 64, 1), 256, 0, stream>>>(
        nrm_bf, WiT, bi, nullptr, nullptr, gv_bf, nullptr, nullptr, nullptr,
        T_TOK, 2048, 1024, 0, W1, W2, W1T, W2T, 11200, 14684);
    conv_gate_kernel<<<(T_TOK * D_MOD / 8 + 255) / 256, 256, 0, stream>>>(gv_bf, conv_w, conv_b, ab_bf);
    mfma_gemm<0, 0, 1, 0, 32, 128, 64, 1><<<dim3(8, 64, 1), 256, 0, stream>>>(
        ab_bf, WodT, bod, h, h, nullptr, nullptr, nullptr, nullptr,
        T_TOK, 1024, 1024, 0, W1, W2, W1T, W2T, 14684, 16384);

    // ---- 4. MoE (top-2 of 8), expert->XCD affinity ----
    rmsnorm_kernel<<<T_TOK, 256, 0, stream>>>(h, w_rms3, nrm, nrm_bf);
    hipMemsetAsync(counts, 0, N_E * sizeof(int), stream);
    route_kernel<<<T_TOK, 256, 0, stream>>>(nrm, w_gate, tIdx, tScore, counts);
    prefix_kernel<<<1, 64, 0, stream>>>(counts, offs, cursor);
    fill_kernel<<<(T_TOK + 255) / 256, 256, 0, stream>>>(tIdx, offs, cursor, list, pairRow);
    // MoE1: 128x256 tile, BK=32, 48KB LDS; grid 16nx*16ny*8e (1-D)
    mfma_gemm<1, 1, 0, 1, 128, 256, 32, 0><<<16 * 16 * 8, 256, 0, stream>>>(
        nrm_bf, W1T, b1, nullptr, nullptr, hsel, list, offs, counts,
        T_TOK, FF_DIM, 1024, 16, nullptr, nullptr, nullptr, nullptr, 0, 0);
    // MoE2: 64x128, BK=32, split-K=2 -> f32 partials
    mfma_gemm<3, 0, 1, 0, 64, 128, 32, 0><<<2 * 8 * 32 * 8, 256, 0, stream>>>(
        hsel, W2T, nullptr, nullptr, ypart, nullptr, list, offs, counts,
        T_TOK, 1024, FF_DIM, 8, nullptr, nullptr, nullptr, nullptr, 0, 0);
    // ---- 5. fused split-K combine + bias + final rmsnorm -> out ----
    combine_rms_kernel<<<T_TOK, 256, 0, stream>>>(ypart, b2, tScore, pairRow, tIdx, h,
                                                  w_rms4, out);
}

// Round 17
// 584.161 us; speedup vs baseline: 1.1631x; 1.1631x over previous
//
#include <hip/hip_runtime.h>
#include <hip/hip_bf16.h>
#include <math.h>

#define T_TOK 2048
#define B_SZ 2
#define L_SEQ 1024
#define D_MOD 1024
#define N_H 16
#define N_KV 4
#define N_CH 8
#define N_E 8
#define FF_DIM 4096
#define DC_K 4
#define EPS_F 1e-6f

typedef unsigned short u16;
typedef unsigned int u32;
typedef short s16x8 __attribute__((ext_vector_type(8)));
typedef u16 u16x8 __attribute__((ext_vector_type(8)));
typedef float f32x4 __attribute__((ext_vector_type(4)));
struct alignas(8) U16x4 { u16 a, b, c, d; };

// lgkm-only barrier: orders LDS traffic without draining in-flight VMEM prefetch
#define BAR_LGKM() asm volatile("s_waitcnt lgkmcnt(0)\n\ts_barrier" ::: "memory")

__device__ __forceinline__ float gelu_exact(float x) {
    return 0.5f * x * (1.0f + erff(x * 0.70710678118654752f));
}
__device__ __forceinline__ u16 f2bf(float f) {  // RNE
    u32 x = __float_as_uint(f);
    return (u16)((x + 0x7fffu + ((x >> 16) & 1u)) >> 16);
}
__device__ __forceinline__ float b2f(u16 u) {
    return __uint_as_float(((u32)u) << 16);
}
__device__ __forceinline__ void gload_lds16(const u16* g, u16* l) {
    __builtin_amdgcn_global_load_lds(
        (const __attribute__((address_space(1))) u32*)g,
        (__attribute__((address_space(3))) u32*)l, 16, 0, 0);
}
// XOR chunk swizzle: cpr=4 (BK=32) -> 2-bit, cpr=8 (BK=64) -> 3-bit
__device__ __forceinline__ int swz(int row, int ch, int cpr) {
    return (cpr == 4) ? (ch ^ ((row >> 1) & 3)) : (ch ^ (row & 7));
}

// ---------------- small-weight transpose + fp32->bf16 (one tile per block) ----------------
struct TDesc {
    const float* src;
    u16* dst;
    int R, C, dstStride, dstRowOff, tileBase, nPerMat;
};
struct TPack { TDesc d[10]; };

__global__ __launch_bounds__(256) void transpose_all(TPack p) {
    __shared__ float ts[64][65];
    int t = blockIdx.x;
    int i = 0;
#pragma unroll
    for (int j = 1; j < 10; ++j)
        if (t >= p.d[j].tileBase) i = j;
    TDesc d = p.d[i];
    int local = t - d.tileBase;
    int e = local / d.nPerMat;
    local -= e * d.nPerMat;
    int ntx = d.C >> 6;
    int bx = local % ntx, by = local / ntx;
    const float* src = d.src + (size_t)e * d.R * d.C + (size_t)(by * 64) * d.C + bx * 64;
    u16* dst = d.dst + (size_t)e * d.C * d.dstStride +
               (size_t)(d.dstRowOff + bx * 64) * d.dstStride + by * 64;
    int tid = threadIdx.x;
#pragma unroll
    for (int k = 0; k < 4; ++k) {
        int fidx = k * 256 + tid;
        int r = fidx >> 4, c4 = (fidx & 15) << 2;
        float4 v = *(const float4*)(src + (size_t)r * d.C + c4);
        ts[r][c4] = v.x; ts[r][c4 + 1] = v.y; ts[r][c4 + 2] = v.z; ts[r][c4 + 3] = v.w;
    }
    __syncthreads();
#pragma unroll
    for (int k = 0; k < 2; ++k) {
        int idx = k * 256 + tid;
        int c = idx >> 3, r8 = (idx & 7) << 3;
        u16x8 o;
#pragma unroll
        for (int j = 0; j < 8; ++j) o[j] = f2bf(ts[r8 + j][c]);
        *(u16x8*)(dst + (size_t)c * d.dstStride + r8) = o;
    }
}

// ---------------- RMSNorm: fp32 in, optional fp32 + bf16 out ----------------
__global__ __launch_bounds__(256) void rmsnorm_kernel(const float* __restrict__ x,
                                                      const float* __restrict__ w,
                                                      float* __restrict__ fo,
                                                      u16* __restrict__ bo) {
    int row = blockIdx.x;
    int tid = threadIdx.x;
    const float* xr = x + (size_t)row * D_MOD;
    float4 v = ((const float4*)xr)[tid];
    float ss = v.x * v.x + v.y * v.y + v.z * v.z + v.w * v.w;
    __shared__ float red[256];
    red[tid] = ss;
    __syncthreads();
    for (int s = 128; s > 0; s >>= 1) {
        if (tid < s) red[tid] += red[tid + s];
        __syncthreads();
    }
    float inv = 1.0f / sqrtf(red[0] * (1.0f / D_MOD) + EPS_F);
    float4 wv = ((const float4*)w)[tid];
    float4 o;
    o.x = v.x * inv * wv.x;
    o.y = v.y * inv * wv.y;
    o.z = v.z * inv * wv.z;
    o.w = v.w * inv * wv.w;
    if (fo) ((float4*)(fo + (size_t)row * D_MOD))[tid] = o;
    if (bo) {
        U16x4 b;
        b.a = f2bf(o.x); b.b = f2bf(o.y); b.c = f2bf(o.z); b.d = f2bf(o.w);
        *(U16x4*)(bo + (size_t)row * D_MOD + tid * 4) = b;
    }
}

// ---------------- MFMA bf16 GEMM (BM x 128, BK in {32,64}) + optional transpose tail ----------------
// MODE 0 dense / 1 MoE gather / 2 MoE compact / 3 MoE compact split-K=2 (f32 partials).
template <int MODE, int GELU, int OUTF, int OUTB, int BM, int BK, int TW>
__global__ __launch_bounds__(256) void mfma_gemm(const u16* __restrict__ A,
                                                 const u16* __restrict__ BT,
                                                 const float* __restrict__ bias,
                                                 const float* __restrict__ res,
                                                 float* __restrict__ C,
                                                 u16* __restrict__ Cb,
                                                 const int* __restrict__ list,
                                                 const int* __restrict__ offs,
                                                 const int* __restrict__ counts,
                                                 int M, int N, int K, int nx,
                                                 const float* __restrict__ tW1,
                                                 const float* __restrict__ tW2,
                                                 u16* __restrict__ tW1T,
                                                 u16* __restrict__ tW2T,
                                                 int tLo, int tHi) {
    constexpr int PWR = BM / 2;
    constexpr int MI = PWR / 16;
    constexpr int NI = 4;
    constexpr int CPR = BK / 8;
    constexpr int AISS = (BM * CPR) / 64;
    constexpr int BISS = (128 * CPR) / 64;
    constexpr int APW = (AISS >= 4) ? (AISS / 4) : 1;
    constexpr int BPW = BISS / 4;
    constexpr int SMG = (2 * BM * BK + 2 * 128 * BK) * 2;
    constexpr int SMT = TW ? (64 * 65 * 4) : 0;
    constexpr int SM = SMG > SMT ? SMG : SMT;
    __shared__ alignas(16) char smem[SM];
    u16* ldsA = (u16*)smem;
    u16* ldsB = ldsA + 2 * BM * BK;
    int tid = threadIdx.x;
    int lane = tid & 63, w = tid >> 6;
    int wr = w >> 1, wc = w & 1;
    int bx, by, e, sk = 0;
    if (MODE == 0) {
        bx = blockIdx.x; by = blockIdx.y; e = 0;
    } else if (MODE == 3) {
        int id = blockIdx.x;
        e = id & 7;
        int r = id >> 3;
        sk = r & 1;
        int q = r >> 1;
        bx = q % nx;
        by = q / nx;
    } else {
        int id = blockIdx.x;
        e = id & 7;
        int r = id >> 3;
        bx = r % nx;
        by = r / nx;
    }
    int cnt, off;
    if (MODE == 0) { cnt = M; off = 0; }
    else { cnt = counts[e]; off = offs[e]; }
    int m0 = by * BM;
    if (m0 < cnt) {  // GEMM body
        int n0 = bx * 128;
        const u16* Bt = BT + (size_t)e * (size_t)N * K;
        int kLo = 0, kHi = K;
        if (MODE == 3) { kLo = sk * (K >> 1); kHi = kLo + (K >> 1); }

        const u16* aSrc[APW];
        const u16* bSrc[BPW];
#pragma unroll
        for (int jp = 0; jp < APW; ++jp) {
            int ii = (AISS >= 4) ? (jp * 4 + w) : w;
            int ci = ii * 64 + lane;
            int rowA = ci / CPR, ch = ci % CPR;
            int rl = m0 + ((rowA < BM) ? rowA : (BM - 1));
            if (rl >= cnt) rl = cnt - 1;
            size_t ga;
            if (MODE == 1) ga = (size_t)list[off + rl] * K;
            else if (MODE >= 2) ga = (size_t)(off + rl) * K;
            else ga = (size_t)rl * K;
            aSrc[jp] = A + ga + (swz(rowA, ch, CPR) << 3);
        }
#pragma unroll
        for (int jp = 0; jp < BPW; ++jp) {
            int ii = jp * 4 + w;
            int ci = ii * 64 + lane;
            int rowB = ci / CPR, ch = ci % CPR;
            bSrc[jp] = Bt + (size_t)(n0 + rowB) * K + (swz(rowB, ch, CPR) << 3);
        }

        auto stage = [&](int buf, int k0) {
#pragma unroll
            for (int jp = 0; jp < APW; ++jp) {
                if (AISS >= 4 || w < AISS) {
                    int ii = (AISS >= 4) ? (jp * 4 + w) : w;
                    gload_lds16(aSrc[jp] + k0, ldsA + buf * (BM * BK) + ii * 512);
                }
            }
#pragma unroll
            for (int jp = 0; jp < BPW; ++jp) {
                int ii = jp * 4 + w;
                gload_lds16(bSrc[jp] + k0, ldsB + buf * (128 * BK) + ii * 512);
            }
        };

        f32x4 acc[MI][NI] = {};
        int r16 = lane & 15, cr = lane >> 4;

        stage(0, kLo);
        __syncthreads();
        int cur = 0;
        for (int k0 = kLo; k0 < kHi; k0 += BK) {
            if (k0 + BK < kHi) stage(cur ^ 1, k0 + BK);
#pragma unroll
            for (int hh = 0; hh < BK / 32; ++hh) {
                s16x8 af[MI], bfr[NI];
#pragma unroll
                for (int mi = 0; mi < MI; ++mi) {
                    int row = wr * PWR + mi * 16 + r16;
                    af[mi] = *(const s16x8*)&ldsA[cur * (BM * BK) + row * BK +
                                                  (swz(row, hh * 4 + cr, CPR) << 3)];
                }
#pragma unroll
                for (int ni = 0; ni < NI; ++ni) {
                    int row = wc * 64 + ni * 16 + r16;
                    bfr[ni] = *(const s16x8*)&ldsB[cur * (128 * BK) + row * BK +
                                                   (swz(row, hh * 4 + cr, CPR) << 3)];
                }
#pragma unroll
                for (int mi = 0; mi < MI; ++mi)
#pragma unroll
                    for (int ni = 0; ni < NI; ++ni)
                        acc[mi][ni] = __builtin_amdgcn_mfma_f32_16x16x32_bf16(
                            af[mi], bfr[ni], acc[mi][ni], 0, 0, 0);
            }
            __syncthreads();
            cur ^= 1;
        }

        const float* bias_e = bias ? (bias + ((MODE && MODE != 3) ? (size_t)e * N : 0)) : nullptr;
        float* Cp = C ? (C + (MODE == 3 ? (size_t)sk * ((size_t)2 * T_TOK * 1024) : (size_t)0))
                      : nullptr;
#pragma unroll
        for (int mi = 0; mi < MI; ++mi) {
#pragma unroll
            for (int ni = 0; ni < NI; ++ni) {
                int rloc = wr * PWR + mi * 16 + (lane >> 4) * 4;
                int col = n0 + wc * 64 + ni * 16 + (lane & 15);
#pragma unroll
                for (int jj = 0; jj < 4; ++jj) {
                    int rl = m0 + rloc + jj;
                    if (rl >= cnt) continue;
                    float val = acc[mi][ni][jj];
                    if (bias_e) val += bias_e[col];
                    if (GELU) val = gelu_exact(val);
                    size_t crow = (MODE == 0) ? (size_t)rl : (size_t)(off + rl);
                    if (res) val += res[crow * N + col];
                    if (OUTF) Cp[crow * N + col] = val;
                    if (OUTB) Cb[crow * N + col] = f2bf(val);
                }
            }
        }
    }

    if constexpr (TW) {
        int nb = gridDim.x * gridDim.y;
        int bid = blockIdx.y * gridDim.x + blockIdx.x;
        float (*ts)[65] = (float(*)[65])smem;
        __syncthreads();
        for (int t = tLo + bid; t < tHi; t += nb) {
            const float* src;
            u16* dst;
            int Cc, ds;
            if (t < 8192) {
                int ee = t >> 10, loc = t & 1023;
                int tbx = loc & 63, tby = loc >> 6;
                src = tW1 + (size_t)ee * 1024 * FF_DIM + (size_t)(tby << 6) * FF_DIM + (tbx << 6);
                dst = tW1T + (size_t)ee * FF_DIM * 1024 + (size_t)(tbx << 6) * 1024 + (tby << 6);
                Cc = FF_DIM; ds = 1024;
            } else {
                int tt = t - 8192;
                int ee = tt >> 10, loc = tt & 1023;
                int tbx = loc & 15, tby = loc >> 4;
                src = tW2 + (size_t)ee * FF_DIM * 1024 + (size_t)(tby << 6) * 1024 + (tbx << 6);
                dst = tW2T + (size_t)ee * 1024 * FF_DIM + (size_t)(tbx << 6) * FF_DIM + (tby << 6);
                Cc = 1024; ds = FF_DIM;
            }
#pragma unroll
            for (int k = 0; k < 4; ++k) {
                int fidx = k * 256 + tid;
                int r = fidx >> 4, c4 = (fidx & 15) << 2;
                float4 v = *(const float4*)(src + (size_t)r * Cc + c4);
                ts[r][c4] = v.x; ts[r][c4 + 1] = v.y; ts[r][c4 + 2] = v.z; ts[r][c4 + 3] = v.w;
            }
            __syncthreads();
#pragma unroll
            for (int k = 0; k < 2; ++k) {
                int idx = k * 256 + tid;
                int c = idx >> 3, r8 = (idx & 7) << 3;
                u16x8 o;
#pragma unroll
                for (int j = 0; j < 8; ++j) o[j] = f2bf(ts[r8 + j][c]);
                *(u16x8*)(dst + (size_t)c * ds + r8) = o;
            }
            __syncthreads();
        }
    }
}

// ---------------- MFMA flash attention, double-buffered K/V with prefetch ----------------
template <int HD>
__global__ __launch_bounds__(256) void mfma_attn(const u16* __restrict__ Qb,
                                                 const u16* __restrict__ Kb,
                                                 const u16* __restrict__ Vb,
                                                 u16* __restrict__ O,
                                                 int stride, int ostride,
                                                 int nh, int nkv, float scale) {
    constexpr int KT = 64;
    constexpr int CH = HD / 8;
    constexpr int NF = HD / 32;
    constexpr int ND = HD / 16;
    constexpr int VSTR = 72;
    constexpr int NISS = (64 * CH) / (64 * 4);
    constexpr int NH2 = HD / 64;

    __shared__ u16 Kl[2][64 * HD];
    __shared__ u16 Vt[2][HD * VSTR];
    __shared__ u16 Pl[4][16 * 72];

    int tid = threadIdx.x, lane = tid & 63, w = tid >> 6;
    int g = lane >> 4, r16 = lane & 15;
    int q0 = blockIdx.x * 64, h = blockIdx.y, b = blockIdx.z;
    int kvh = h / (nh / nkv);

    const u16* Qp = Qb + (size_t)(b * L_SEQ + q0 + w * 16 + r16) * stride + h * HD + g * 8;
    s16x8 qf[NF];
#pragma unroll
    for (int f = 0; f < NF; ++f) qf[f] = *(const s16x8*)(Qp + f * 32);

    const u16* Kbase = Kb + (size_t)(b * L_SEQ) * stride + (size_t)kvh * HD;
    const u16* Vbase = Vb + (size_t)(b * L_SEQ) * stride + (size_t)kvh * HD;

    int srcOffK[NISS];
#pragma unroll
    for (int i = 0; i < NISS; ++i) {
        int ci = (w * NISS + i) * 64 + lane;
        int row = ci / CH;
        int ch = ci % CH;
        srcOffK[i] = row * stride + ((ch ^ (row & 7)) << 3);
    }

    u16x8 vr[2 * NH2];
    auto vload = [&](int kt) {
        const u16* Vs = Vbase + (size_t)(kt * KT) * stride + (size_t)lane * stride;
#pragma unroll
        for (int half = 0; half < NH2; ++half) {
            int dbase = w * 16 + half * 64;
            vr[2 * half] = *(const u16x8*)(Vs + dbase);
            vr[2 * half + 1] = *(const u16x8*)(Vs + dbase + 8);
        }
    };

    f32x4 ofr[ND] = {};
    float m_r[4], l_r[4];
#pragma unroll
    for (int r = 0; r < 4; ++r) { m_r[r] = -1e30f; l_r[r] = 0.f; }

    constexpr int NT = L_SEQ / KT;
#pragma unroll
    for (int i = 0; i < NISS; ++i)
        gload_lds16(Kbase + srcOffK[i], &Kl[0][(w * NISS + i) * 512]);
    vload(0);

    for (int kt = 0; kt < NT; ++kt) {
        int cur = kt & 1;
#pragma unroll
        for (int half = 0; half < NH2; ++half) {
            int dbase = w * 16 + half * 64;
#pragma unroll
            for (int j = 0; j < 8; ++j) {
                Vt[cur][(dbase + j) * VSTR + lane] = vr[2 * half][j];
                Vt[cur][(dbase + 8 + j) * VSTR + lane] = vr[2 * half + 1][j];
            }
        }
        __syncthreads();
        if (kt + 1 < NT) {
            const u16* Ksrc2 = Kbase + (size_t)((kt + 1) * KT) * stride;
#pragma unroll
            for (int i = 0; i < NISS; ++i)
                gload_lds16(Ksrc2 + srcOffK[i], &Kl[cur ^ 1][(w * NISS + i) * 512]);
            vload(kt + 1);
        }

        f32x4 s[4];
        __builtin_amdgcn_s_setprio(1);
#pragma unroll
        for (int sub = 0; sub < 4; ++sub) {
            f32x4 acc = {};
#pragma unroll
            for (int f = 0; f < NF; ++f) {
                int row = sub * 16 + r16;
                int chunk = (f * 4 + g) ^ (row & 7);
                s16x8 kf = *(const s16x8*)&Kl[cur][(row * CH + chunk) * 8];
                acc = __builtin_amdgcn_mfma_f32_16x16x32_bf16(qf[f], kf, acc, 0, 0, 0);
            }
            s[sub] = acc;
        }
        __builtin_amdgcn_s_setprio(0);

#pragma unroll
        for (int sub = 0; sub < 4; ++sub)
#pragma unroll
            for (int r = 0; r < 4; ++r) s[sub][r] *= scale;
#pragma unroll
        for (int r = 0; r < 4; ++r) {
            float mx = fmaxf(fmaxf(s[0][r], s[1][r]), fmaxf(s[2][r], s[3][r]));
            mx = fmaxf(mx, __shfl_xor(mx, 1));
            mx = fmaxf(mx, __shfl_xor(mx, 2));
            mx = fmaxf(mx, __shfl_xor(mx, 4));
            mx = fmaxf(mx, __shfl_xor(mx, 8));
            float mo = m_r[r];
            float mn = fmaxf(mo, mx);
            float sc = __expf(mo - mn);
            m_r[r] = mn;
            float sum = 0.f;
#pragma unroll
            for (int sub = 0; sub < 4; ++sub) {
                float e = __expf(s[sub][r] - mn);
                s[sub][r] = e;
                sum += e;
            }
            sum += __shfl_xor(sum, 1);
            sum += __shfl_xor(sum, 2);
            sum += __shfl_xor(sum, 4);
            sum += __shfl_xor(sum, 8);
            l_r[r] = l_r[r] * sc + sum;
#pragma unroll
            for (int dsub = 0; dsub < ND; ++dsub) ofr[dsub][r] *= sc;
        }

        u16* Pw = Pl[w];
#pragma unroll
        for (int sub = 0; sub < 4; ++sub)
#pragma unroll
            for (int r = 0; r < 4; ++r) {
                int q = g * 4 + r;
                int k = sub * 16 + r16;
                Pw[q * 72 + (((k >> 3) ^ (q & 7)) << 3) + (k & 7)] = f2bf(s[sub][r]);
            }
        BAR_LGKM();

        s16x8 pf[2];
#pragma unroll
        for (int ks = 0; ks < 2; ++ks) {
            int chunk = (ks * 4 + g) ^ (r16 & 7);
            pf[ks] = *(const s16x8*)&Pw[r16 * 72 + chunk * 8];
        }
        __builtin_amdgcn_s_setprio(1);
#pragma unroll
        for (int dsub = 0; dsub < ND; ++dsub)
#pragma unroll
            for (int ks = 0; ks < 2; ++ks) {
                s16x8 vf = *(const s16x8*)&Vt[cur][(dsub * 16 + r16) * VSTR + ks * 32 + g * 8];
                ofr[dsub] = __builtin_amdgcn_mfma_f32_16x16x32_bf16(pf[ks], vf, ofr[dsub], 0, 0, 0);
            }
        __builtin_amdgcn_s_setprio(0);
    }

    float inv[4];
#pragma unroll
    for (int r = 0; r < 4; ++r) inv[r] = 1.0f / l_r[r];
#pragma unroll
    for (int dsub = 0; dsub < ND; ++dsub)
#pragma unroll
        for (int r = 0; r < 4; ++r) {
            int q = q0 + w * 16 + g * 4 + r;
            O[(size_t)(b * L_SEQ + q) * ostride + h * HD + dsub * 16 + r16] =
                f2bf(ofr[dsub][r] * inv[r]);
        }
}

// ---------------- DeltaNet conv + gate (vectorized u16x8) ----------------
__global__ __launch_bounds__(256) void conv_gate_kernel(const u16* __restrict__ gv,
                                                        const float* __restrict__ cw,
                                                        const float* __restrict__ cb,
                                                        u16* __restrict__ gated) {
    int idx = blockIdx.x * 256 + threadIdx.x;
    if (idx >= T_TOK * D_MOD / 8) return;
    int d8 = (idx & 127) << 3;
    int t = idx >> 7;
    int l = t & (L_SEQ - 1);
    float conv[8];
#pragma unroll
    for (int j = 0; j < 8; ++j) conv[j] = cb[d8 + j];
#pragma unroll
    for (int i = 0; i < DC_K; ++i) {
        int lp = l - (DC_K - 1) + i;
        if (lp >= 0) {
            u16x8 v8 = *(const u16x8*)(gv + (size_t)(t - l + lp) * (2 * D_MOD) + D_MOD + d8);
#pragma unroll
            for (int j = 0; j < 8; ++j) conv[j] += b2f(v8[j]) * cw[(d8 + j) * DC_K + i];
        }
    }
    u16x8 g8 = *(const u16x8*)(gv + (size_t)t * (2 * D_MOD) + d8);
    u16x8 o;
#pragma unroll
    for (int j = 0; j < 8; ++j) {
        float gate = b2f(g8[j]);
        float sig = 1.0f / (1.0f + expf(-gate));
        o[j] = f2bf(conv[j] * (gate * sig));
    }
    *(u16x8*)(gated + (size_t)t * D_MOD + d8) = o;
}

// ---------------- MoE routing (fp32 input) ----------------
__global__ __launch_bounds__(256) void route_kernel(const float* __restrict__ g,
                                                    const float* __restrict__ wg,
                                                    int* __restrict__ tIdx,
                                                    float* __restrict__ tScore,
                                                    int* __restrict__ counts) {
    int t = blockIdx.x, tid = threadIdx.x;
    __shared__ float gs[D_MOD];
    __shared__ float logits[N_E];
    ((float4*)gs)[tid] = ((const float4*)(g + (size_t)t * D_MOD))[tid];
    __syncthreads();
    int e = tid >> 5, lane = tid & 31;
    const float* w = wg + (size_t)e * D_MOD;
    float p = 0.f;
    for (int d = lane; d < D_MOD; d += 32) p += gs[d] * w[d];
    for (int o = 16; o > 0; o >>= 1) p += __shfl_down(p, o, 32);
    if (lane == 0) logits[e] = p;
    __syncthreads();
    if (tid == 0) {
        float mx = logits[0];
        for (int e2 = 1; e2 < N_E; ++e2) mx = fmaxf(mx, logits[e2]);
        float pe[N_E];
        float Z = 0.f;
        for (int e2 = 0; e2 < N_E; ++e2) {
            pe[e2] = expf(logits[e2] - mx);
            Z += pe[e2];
        }
        int i0 = 0;
        float b0 = pe[0];
        for (int e2 = 1; e2 < N_E; ++e2)
            if (pe[e2] > b0) { b0 = pe[e2]; i0 = e2; }
        int i1 = -1;
        float b1 = -1.f;
        for (int e2 = 0; e2 < N_E; ++e2)
            if (e2 != i0 && pe[e2] > b1) { b1 = pe[e2]; i1 = e2; }
        float invZ = 1.0f / Z;
        tIdx[t * 2] = i0;
        tIdx[t * 2 + 1] = i1;
        tScore[t * 2] = b0 * invZ;
        tScore[t * 2 + 1] = b1 * invZ;
        atomicAdd(&counts[i0], 1);
        atomicAdd(&counts[i1], 1);
    }
}

__global__ void prefix_kernel(const int* __restrict__ counts, int* __restrict__ offs,
                              int* __restrict__ cursor) {
    if (threadIdx.x == 0) {
        int acc = 0;
        for (int e = 0; e < N_E; ++e) {
            offs[e] = acc;
            acc += counts[e];
            cursor[e] = 0;
        }
    }
}

__global__ __launch_bounds__(256) void fill_kernel(const int* __restrict__ tIdx,
                                                   const int* __restrict__ offs,
                                                   int* __restrict__ cursor,
                                                   int* __restrict__ list,
                                                   int* __restrict__ pairRow) {
    int t = blockIdx.x * 256 + threadIdx.x;
    if (t >= T_TOK) return;
    for (int kk = 0; kk < 2; ++kk) {
        int e = tIdx[t * 2 + kk];
        int pos = atomicAdd(&cursor[e], 1);
        int slot = offs[e] + pos;
        list[slot] = t;
        pairRow[t * 2 + kk] = slot;
    }
}

// ---------------- fused MoE combine (split-K partials + bias) + final RMSNorm ----------------
__global__ __launch_bounds__(256) void combine_rms_kernel(const float* __restrict__ yp,
                                                          const float* __restrict__ b2,
                                                          const float* __restrict__ tScore,
                                                          const int* __restrict__ pairRow,
                                                          const int* __restrict__ tIdx,
                                                          const float* __restrict__ h,
                                                          const float* __restrict__ w,
                                                          float* __restrict__ out) {
    const size_t HALF = (size_t)2 * T_TOK * D_MOD;
    int row = blockIdx.x;
    int tid = threadIdx.x;
    float4 v = ((const float4*)(h + (size_t)row * D_MOD))[tid];
#pragma unroll
    for (int kk = 0; kk < 2; ++kk) {
        int r = pairRow[row * 2 + kk];
        int e = tIdx[row * 2 + kk];
        float s = tScore[row * 2 + kk];
        float4 y0 = ((const float4*)(yp + (size_t)r * D_MOD))[tid];
        float4 y1 = ((const float4*)(yp + HALF + (size_t)r * D_MOD))[tid];
        float4 bb = ((const float4*)(b2 + (size_t)e * D_MOD))[tid];
        v.x += s * (y0.x + y1.x + bb.x);
        v.y += s * (y0.y + y1.y + bb.y);
        v.z += s * (y0.z + y1.z + bb.z);
        v.w += s * (y0.w + y1.w + bb.w);
    }
    __shared__ float red[256];
    red[tid] = v.x * v.x + v.y * v.y + v.z * v.z + v.w * v.w;
    __syncthreads();
    for (int s = 128; s > 0; s >>= 1) {
        if (tid < s) red[tid] += red[tid + s];
        __syncthreads();
    }
    float inv = 1.0f / sqrtf(red[0] * (1.0f / D_MOD) + EPS_F);
    float4 wv = ((const float4*)w)[tid];
    float4 o;
    o.x = v.x * inv * wv.x;
    o.y = v.y * inv * wv.y;
    o.z = v.z * inv * wv.z;
    o.w = v.w * inv * wv.w;
    ((float4*)(out + (size_t)row * D_MOD))[tid] = o;
}

extern "C" void kernel_launch(void* const* d_in, const int* in_sizes, int n_in,
                              void* d_out, int out_size, void* d_ws, size_t ws_size,
                              hipStream_t stream) {
    const float* x = (const float*)d_in[0];
    const float* w_rms1 = (const float*)d_in[2];
    const float* w_rms2 = (const float*)d_in[3];
    const float* w_rms3 = (const float*)d_in[4];
    const float* w_rms4 = (const float*)d_in[5];
    const float* Wq = (const float*)d_in[6];
    const float* Wk = (const float*)d_in[7];
    const float* Wv = (const float*)d_in[8];
    const float* Wo = (const float*)d_in[9];
    const float* Cq = (const float*)d_in[10];
    const float* Ck = (const float*)d_in[11];
    const float* Cv = (const float*)d_in[12];
    const float* Co = (const float*)d_in[13];
    const float* Wi = (const float*)d_in[14];
    const float* bi = (const float*)d_in[15];
    const float* conv_w = (const float*)d_in[16];
    const float* conv_b = (const float*)d_in[17];
    const float* Wod = (const float*)d_in[18];
    const float* bod = (const float*)d_in[19];
    const float* w_gate = (const float*)d_in[20];
    const float* W1 = (const float*)d_in[21];
    const float* b1 = (const float*)d_in[22];
    const float* W2 = (const float*)d_in[23];
    const float* b2 = (const float*)d_in[24];
    float* out = (float*)d_out;

    char* ws = (char*)d_ws;
    size_t off = 0;
    auto alloc_f = [&](size_t n) { float* p = (float*)(ws + off); off += n * 4; return p; };
    auto alloc_b = [&](size_t n) { u16* p = (u16*)(ws + off); off += n * 2; return p; };

    u16* qkvT = alloc_b((size_t)1536 * 1024);
    u16* cqkvT = alloc_b((size_t)3072 * 1024);
    u16* WoT = alloc_b((size_t)1024 * 1024);
    u16* CoT = alloc_b((size_t)1024 * 1024);
    u16* WiT = alloc_b((size_t)2048 * 1024);
    u16* WodT = alloc_b((size_t)1024 * 1024);
    u16* W1T = alloc_b((size_t)N_E * FF_DIM * 1024);
    u16* W2T = alloc_b((size_t)N_E * 1024 * FF_DIM);
    const size_t TD = (size_t)T_TOK * D_MOD;
    float* h = alloc_f(TD);
    float* nrm = alloc_f(TD);
    u16* nrm_bf = alloc_b(TD);
    u16* h_bf = alloc_b(TD);
    u16* ab_bf = alloc_b(TD);
    u16* qkv_bf = alloc_b((size_t)T_TOK * 3072);
    u16* gv_bf = alloc_b((size_t)T_TOK * 2048);
    u16* hsel = alloc_b((size_t)2 * T_TOK * FF_DIM);
    float* ypart = alloc_f((size_t)2 * 2 * T_TOK * D_MOD);
    int* counts = (int*)(ws + off); off += N_E * 4;
    int* offs = (int*)(ws + off); off += N_E * 4;
    int* cursor = (int*)(ws + off); off += N_E * 4;
    int* tIdx = (int*)(ws + off); off += 2 * T_TOK * 4;
    int* list = (int*)(ws + off); off += 2 * T_TOK * 4;
    int* pairRow = (int*)(ws + off); off += 2 * T_TOK * 4;
    float* tScore = alloc_f(2 * T_TOK);

    // ---- 0. small-weight transposes ----
    TPack tp;
    int tb = 0;
    auto mkd = [&](int i, const float* s, u16* d, int R, int C, int ds, int ro) {
        int per = (C >> 6) * (R >> 6);
        tp.d[i] = TDesc{s, d, R, C, ds, ro, tb, per};
        tb += per;
    };
    mkd(0, Wq, qkvT, 1024, 1024, 1024, 0);
    mkd(1, Wk, qkvT, 1024, 256, 1024, 1024);
    mkd(2, Wv, qkvT, 1024, 256, 1024, 1280);
    mkd(3, Cq, cqkvT, 1024, 1024, 1024, 0);
    mkd(4, Ck, cqkvT, 1024, 1024, 1024, 1024);
    mkd(5, Cv, cqkvT, 1024, 1024, 1024, 2048);
    mkd(6, Wo, WoT, 1024, 1024, 1024, 0);
    mkd(7, Co, CoT, 1024, 1024, 1024, 0);
    mkd(8, Wi, WiT, 1024, 2048, 1024, 0);
    mkd(9, Wod, WodT, 1024, 1024, 1024, 0);
    transpose_all<<<tb, 256, 0, stream>>>(tp);

    // ---- 1. attn1; dense GEMMs (BK=64) carry W1/W2 transpose tiles ----
    rmsnorm_kernel<<<T_TOK, 256, 0, stream>>>(x, w_rms1, nullptr, nrm_bf);
    mfma_gemm<0, 0, 0, 1, 32, 64, 1><<<dim3(12, 64, 1), 256, 0, stream>>>(
        nrm_bf, qkvT, nullptr, nullptr, nullptr, qkv_bf, nullptr, nullptr, nullptr,
        T_TOK, 1536, 1024, 0, W1, W2, W1T, W2T, 0, 2600);
    mfma_attn<64><<<dim3(16, N_H, B_SZ), 256, 0, stream>>>(
        qkv_bf, qkv_bf + 1024, qkv_bf + 1280, ab_bf, 1536, 1024, N_H, N_KV, 0.125f);
    mfma_gemm<0, 0, 1, 1, 32, 64, 1><<<dim3(8, 64, 1), 256, 0, stream>>>(
        ab_bf, WoT, nullptr, x, h, h_bf, nullptr, nullptr, nullptr,
        T_TOK, 1024, 1024, 0, W1, W2, W1T, W2T, 2600, 4300);

    // ---- 2. ContextManager attention ----
    mfma_gemm<0, 0, 0, 1, 32, 64, 1><<<dim3(24, 64, 1), 256, 0, stream>>>(
        h_bf, cqkvT, nullptr, nullptr, nullptr, qkv_bf, nullptr, nullptr, nullptr,
        T_TOK, 3072, 1024, 0, W1, W2, W1T, W2T, 4300, 9500);
    mfma_attn<128><<<dim3(16, N_CH, B_SZ), 256, 0, stream>>>(
        qkv_bf, qkv_bf + 1024, qkv_bf + 2048, ab_bf, 3072, 1024, N_CH, N_CH,
        0.088388347648318447f);
    mfma_gemm<0, 0, 1, 0, 32, 64, 1><<<dim3(8, 64, 1), 256, 0, stream>>>(
        ab_bf, CoT, nullptr, h, h, nullptr, nullptr, nullptr, nullptr,
        T_TOK, 1024, 1024, 0, W1, W2, W1T, W2T, 9500, 11200);

    // ---- 3. deltanet ----
    rmsnorm_kernel<<<T_TOK, 256, 0, stream>>>(h, w_rms2, nullptr, nrm_bf);
    mfma_gemm<0, 0, 0, 1, 32, 64, 1><<<dim3(16, 64, 1), 256, 0, stream>>>(
        nrm_bf, WiT, bi, nullptr, nullptr, gv_bf, nullptr, nullptr, nullptr,
        T_TOK, 2048, 1024, 0, W1, W2, W1T, W2T, 11200, 14684);
    conv_gate_kernel<<<(T_TOK * D_MOD / 8 + 255) / 256, 256, 0, stream>>>(gv_bf, conv_w, conv_b, ab_bf);
    mfma_gemm<0, 0, 1, 0, 32, 64, 1><<<dim3(8, 64, 1), 256, 0, stream>>>(
        ab_bf, WodT, bod, h, h, nullptr, nullptr, nullptr, nullptr,
        T_TOK, 1024, 1024, 0, W1, W2, W1T, W2T, 14684, 16384);

    // ---- 4. MoE (top-2 of 8), expert->XCD affinity ----
    rmsnorm_kernel<<<T_TOK, 256, 0, stream>>>(h, w_rms3, nrm, nrm_bf);
    hipMemsetAsync(counts, 0, N_E * sizeof(int), stream);
    route_kernel<<<T_TOK, 256, 0, stream>>>(nrm, w_gate, tIdx, tScore, counts);
    prefix_kernel<<<1, 64, 0, stream>>>(counts, offs, cursor);
    fill_kernel<<<(T_TOK + 255) / 256, 256, 0, stream>>>(tIdx, offs, cursor, list, pairRow);
    // MoE1: 128x128, BK=32, 32KB LDS, ~4 blocks/CU (proven R15 config)
    mfma_gemm<1, 1, 0, 1, 128, 32, 0><<<32 * 16 * 8, 256, 0, stream>>>(
        nrm_bf, W1T, b1, nullptr, nullptr, hsel, list, offs, counts,
        T_TOK, FF_DIM, 1024, 32, nullptr, nullptr, nullptr, nullptr, 0, 0);
    // MoE2: 64x128, BK=32, split-K=2 -> f32 partials
    mfma_gemm<3, 0, 1, 0, 64, 32, 0><<<2 * 8 * 32 * 8, 256, 0, stream>>>(
        hsel, W2T, nullptr, nullptr, ypart, nullptr, list, offs, counts,
        T_TOK, 1024, FF_DIM, 8, nullptr, nullptr, nullptr, nullptr, 0, 0);
    // ---- 5. fused split-K combine + bias + final rmsnorm -> out ----
    combine_rms_kernel<<<T_TOK, 256, 0, stream>>>(ypart, b2, tScore, pairRow, tIdx, h,
                                                  w_rms4, out);
}